// Round 5
// baseline (629.511 us; speedup 1.0000x reference)
//
#include <hip/hip_runtime.h>

#define HID 64
#define NGr 16
#define NPG 160
#define NN  2560            // NGr*NPG
#define EE  40960
#define PPG 25600           // NPG*NPG
#define PT  409600          // NGr*PPG
#define TT  25600           // PT/16 tiles (16 pairs each)
#define TPG 1600            // tiles per graph
#define AV  64
#define BV  8
#define EPSB 1e-5f

typedef __attribute__((ext_vector_type(8))) short short8v;   // 8 bf16 (4 VGPRs)
typedef __attribute__((ext_vector_type(4))) float f32x4;

static __device__ __forceinline__ unsigned short bf16_hi(float v) {   // truncate
    return (unsigned short)(__float_as_uint(v) >> 16);
}
static __device__ __forceinline__ unsigned short bf16_rn(float v) {   // round-nearest-even
    unsigned int u = __float_as_uint(v);
    u += 0x7FFFu + ((u >> 16) & 1u);
    return (unsigned short)(u >> 16);
}
static __device__ __forceinline__ float bf16_val(unsigned short h) {
    return __uint_as_float(((unsigned int)h) << 16);
}

// ---------------- prep: combined first-layer weights ----------------
__global__ void k_prep(const float* __restrict__ W1, const float* __restrict__ b1,
                       const float* __restrict__ W2, const float* __restrict__ b2,
                       const float* __restrict__ We, const float* __restrict__ be,
                       const float* __restrict__ L0w, const float* __restrict__ L0b,
                       float* __restrict__ W1c, float* __restrict__ W2c, float* __restrict__ Wec,
                       float* __restrict__ b1c, float* __restrict__ b2c, float* __restrict__ bec) {
    int blk = blockIdx.x, tid = threadIdx.x;
    const float* Wsrc = (blk == 0) ? W1 : (blk == 1) ? W2 : We;
    const float* bsrc = (blk == 0) ? b1 : (blk == 1) ? b2 : be;
    const float* L    = L0w + blk * 64 * 64;
    float* Wdst = (blk == 0) ? W1c : (blk == 1) ? W2c : Wec;
    float* bdst = (blk == 0) ? b1c : (blk == 1) ? b2c : bec;
    for (int idx = tid; idx < 4096; idx += 256) {
        int k = idx >> 6, h = idx & 63;
        float acc = 0.f;
        for (int m = 0; m < 64; ++m) acc = fmaf(Wsrc[k * 64 + m], L[m * 64 + h], acc);
        Wdst[idx] = acc;
    }
    if (tid < 64) {
        int h = tid;
        float acc = (blk == 0) ? L0b[h] : 0.f;
        for (int m = 0; m < 64; ++m) acc = fmaf(bsrc[m], L[m * 64 + h], acc);
        bdst[h] = acc;
    }
}

// ---------------- nodes: x_emb -> A, B (2560 x 64 each) ----------------
__global__ void k_nodes(const float* __restrict__ atab, const int* __restrict__ x,
                        const float* __restrict__ W1c, const float* __restrict__ W2c,
                        const float* __restrict__ b1c, const float* __restrict__ b2c,
                        float* __restrict__ A, float* __restrict__ Bm) {
    int n = blockIdx.x, h = threadIdx.x;
    __shared__ float xe[64];
    float v = 0.f;
#pragma unroll
    for (int c = 0; c < 9; ++c) v += atab[c * AV * HID + x[n * 9 + c] * HID + h];
    xe[h] = v;
    __syncthreads();
    float a = b1c[h], b = b2c[h];
#pragma unroll
    for (int k = 0; k < 64; ++k) {
        float xk = xe[k];
        a = fmaf(xk, W1c[k * 64 + h], a);
        b = fmaf(xk, W2c[k * 64 + h], b);
    }
    A[n * 64 + h] = a;
    Bm[n * 64 + h] = b;
}

// ---------------- gstats: analytic BN0 stats from A,B (dense part) ----------------
__global__ void k_gstats(const float* __restrict__ A, const float* __restrict__ Bm,
                         float* __restrict__ stats) {
    int g = blockIdx.x;
    int h = threadIdx.x & 63, w = threadIdx.x >> 6;
    float sA = 0.f, sA2 = 0.f, sB = 0.f, sB2 = 0.f;
    for (int n = w; n < NPG; n += 4) {
        float a = A[(size_t)(g * NPG + n) * 64 + h];
        float b = Bm[(size_t)(g * NPG + n) * 64 + h];
        sA += a; sA2 = fmaf(a, a, sA2);
        sB += b; sB2 = fmaf(b, b, sB2);
    }
    __shared__ float ls[4][4][64];
    ls[w][0][h] = sA; ls[w][1][h] = sA2; ls[w][2][h] = sB; ls[w][3][h] = sB2;
    __syncthreads();
    if (w == 0) {
        sA  = ls[0][0][h] + ls[1][0][h] + ls[2][0][h] + ls[3][0][h];
        sA2 = ls[0][1][h] + ls[1][1][h] + ls[2][1][h] + ls[3][1][h];
        sB  = ls[0][2][h] + ls[1][2][h] + ls[2][2][h] + ls[3][2][h];
        sB2 = ls[0][3][h] + ls[1][3][h] + ls[2][3][h] + ls[3][3][h];
        atomicAdd(&stats[h], 160.f * (sA + sB));
        atomicAdd(&stats[64 + h], 160.f * (sA2 + sB2) + 2.f * sA * sB);
    }
}

// ---------------- edges: ew -> ewf; sum0 += ew; bucket counts ----------------
__global__ void __launch_bounds__(256) k_edges(const float* __restrict__ btab, const int* __restrict__ eattr,
                                               const int* __restrict__ epos,
                                               const float* __restrict__ Wec, const float* __restrict__ bec,
                                               float* __restrict__ ewf, float* __restrict__ stats,
                                               int* __restrict__ bcount) {
    int h = threadIdx.x & 63;
    int el = threadIdx.x >> 6;
    __shared__ float ea[4][64];
    float ssum = 0.f;
    for (int base = blockIdx.x * 4; base < EE; base += gridDim.x * 4) {
        int e = base + el;
        float v = 0.f;
#pragma unroll
        for (int c = 0; c < 3; ++c) v += btab[c * BV * HID + eattr[e * 3 + c] * HID + h];
        ea[el][h] = v;                   // wave-local, wave-synchronous
        float ew = bec[h];
#pragma unroll
        for (int k = 0; k < 64; ++k) ew = fmaf(ea[el][k], Wec[k * 64 + h], ew);
        ewf[(size_t)e * 64 + h] = ew;
        ssum += ew;
        if (h == 0) atomicAdd(&bcount[epos[e] >> 4], 1);
    }
    atomicAdd(&stats[h], ssum);
}

// ---------------- scan: exclusive prefix of bcount[TT] -> boffs, bcursor ----------------
__global__ void k_scan(const int* __restrict__ bcount, int* __restrict__ boffs,
                       int* __restrict__ bcursor) {
    __shared__ int part[256];
    int tid = threadIdx.x;
    int base = tid * (TT / 256);
    int s = 0;
    for (int q = 0; q < TT / 256; ++q) s += bcount[base + q];
    part[tid] = s;
    __syncthreads();
    for (int d = 1; d < 256; d <<= 1) {
        int v = (tid >= d) ? part[tid - d] : 0;
        __syncthreads();
        part[tid] += v;
        __syncthreads();
    }
    int run = part[tid] - s;   // exclusive prefix
    for (int q = 0; q < TT / 256; ++q) {
        int c = bcount[base + q];
        boffs[base + q] = run;
        bcursor[base + q] = run;
        run += c;
    }
    if (tid == 255) boffs[TT] = run;
}

// ---------------- fill: elist[slot] = (e<<4) | jslot ----------------
__global__ void k_fill(const int* __restrict__ epos, int* __restrict__ bcursor,
                       int* __restrict__ elist) {
    int e = blockIdx.x * 256 + threadIdx.x;
    if (e >= EE) return;
    int p = epos[e];
    int t = p >> 4, jj = p & 15;
    int slot = atomicAdd(&bcursor[t], 1);
    elist[slot] = (e << 4) | jj;
}

// ---------------- scorr: sparse ss0 correction ----------------
__global__ void __launch_bounds__(256) k_scorr(const float* __restrict__ A, const float* __restrict__ Bm,
                                               const float* __restrict__ ewf,
                                               const int* __restrict__ boffs, const int* __restrict__ elist,
                                               float* __restrict__ stats) {
    __shared__ float run[4][16][64];
    int h = threadIdx.x & 63, w = threadIdx.x >> 6;
#pragma unroll
    for (int jj = 0; jj < 16; ++jj) run[w][jj][h] = 0.f;
    float ssacc = 0.f;
    int wave = blockIdx.x * 4 + w;
    int nw = gridDim.x * 4;
    for (int t = wave; t < TT; t += nw) {
        int be = boffs[t], en = boffs[t + 1];
        if (be == en) continue;
        int g = t / TPG;
        int rem = t - g * TPG;
        int i = rem / 10;
        int j0 = (rem - i * 10) << 4;
        float a = A[(size_t)(g * NPG + i) * 64 + h];
        for (int q = be; q < en; ++q) {
            int pk = elist[q];
            int e = pk >> 4, jj = pk & 15;
            float ew = ewf[(size_t)e * 64 + h];
            float base = a + Bm[(size_t)(g * NPG + j0 + jj) * 64 + h];
            float r = run[w][jj][h];
            ssacc += 2.f * (base + r) * ew + ew * ew;
            run[w][jj][h] = r + ew;
        }
        for (int q = be; q < en; ++q) run[w][elist[q] & 15][h] = 0.f;
    }
    atomicAdd(&stats[64 + h], ssacc);
}

// ---------------- wprep: fold BN0 scale into L1w; pre-swizzled MFMA frags + transpose ----------------
// h0 = relu(s0*z+t0) = s0*relu(z - mp), mp = -t0/s0  (s0>0 since g0==1)
// W'[h][c] = s0[h]*L1w[h][c] (bf16 rn);  z1 = relu(z-mp) @ W' + b1
__global__ void k_wprep(const float* __restrict__ L1w,
                        const float* __restrict__ g0, const float* __restrict__ beta0,
                        const float* __restrict__ stats,
                        float* __restrict__ mprime,
                        unsigned short* __restrict__ WFRAG, unsigned short* __restrict__ WT) {
    __shared__ float s0s[64];
    int tid = threadIdx.x;
    const float invP = 1.f / (float)PT;
    if (tid < 64) {
        float mu = stats[tid] * invP;
        float var = stats[64 + tid] * invP - mu * mu;
        float inv = rsqrtf(var + EPSB);
        float s0 = g0[tid] * inv;
        float t0 = fmaf(-mu, s0, beta0[tid]);
        s0s[tid] = s0;
        mprime[tid] = -t0 / s0;
    }
    __syncthreads();
    for (int idx = tid; idx < 4096; idx += 256) {
        int h = idx >> 6, c = idx & 63;
        unsigned short w = bf16_rn(s0s[h] * L1w[idx]);
        int lane = ((h >> 3) & 3) * 16 + (c & 15);
        WFRAG[(((c >> 4) * 2 + (h >> 5)) * 64 + lane) * 8 + (h & 7)] = w;
        WT[c * 64 + h] = w;
    }
}

// ---------------- main: dense z1 = relu(z0-mp)@W' + b1, packed bf16 store, stats1 ----------------
// A-frag: lane -> row (l&15), k = (l>>4)*8+j per K-half; D: col=l&15, row=(l>>4)*4+reg
__global__ void __launch_bounds__(256, 4) k_main(const unsigned short* __restrict__ WFRAG,
                                                 const float* __restrict__ mprime,
                                                 const float* __restrict__ L1b,
                                                 const float* __restrict__ A, const float* __restrict__ Bm,
                                                 uint2* __restrict__ zpk, float* __restrict__ stats) {
    int lane = threadIdx.x & 63;
    int wid = blockIdx.x * 4 + (threadIdx.x >> 6);
    int nW = gridDim.x * 4;
    int r16 = lane & 15, kg = lane >> 4;

    short8v Wf[4][2];
#pragma unroll
    for (int ct = 0; ct < 4; ++ct)
#pragma unroll
        for (int ks = 0; ks < 2; ++ks)
            Wf[ct][ks] = *reinterpret_cast<const short8v*>(WFRAG + (((ct * 2 + ks) * 64) + lane) * 8);
    float4 m0 = *reinterpret_cast<const float4*>(mprime + kg * 8);
    float4 m1 = *reinterpret_cast<const float4*>(mprime + kg * 8 + 4);
    float4 m2 = *reinterpret_cast<const float4*>(mprime + 32 + kg * 8);
    float4 m3 = *reinterpret_cast<const float4*>(mprime + 32 + kg * 8 + 4);
    float mpa[8] = {m0.x, m0.y, m0.z, m0.w, m1.x, m1.y, m1.z, m1.w};
    float mpb[8] = {m2.x, m2.y, m2.z, m2.w, m3.x, m3.y, m3.z, m3.w};
    float biasv[4];
#pragma unroll
    for (int ct = 0; ct < 4; ++ct) biasv[ct] = L1b[ct * 16 + r16];

    float sum[4] = {0.f, 0.f, 0.f, 0.f}, ssum[4] = {0.f, 0.f, 0.f, 0.f};

    for (int tile = wid; tile < TT; tile += nW) {
        int g = tile / TPG;
        int rem = tile - g * TPG;
        int i = rem / 10;
        int j0 = (rem - i * 10) << 4;
        const float* Ar = A + (size_t)(g * NPG + i) * 64;
        const float* Br = Bm + (size_t)(g * NPG + j0 + r16) * 64;
        float4 a0 = *reinterpret_cast<const float4*>(Ar + kg * 8);
        float4 a1 = *reinterpret_cast<const float4*>(Ar + kg * 8 + 4);
        float4 a2 = *reinterpret_cast<const float4*>(Ar + 32 + kg * 8);
        float4 a3 = *reinterpret_cast<const float4*>(Ar + 32 + kg * 8 + 4);
        float4 b0 = *reinterpret_cast<const float4*>(Br + kg * 8);
        float4 b1 = *reinterpret_cast<const float4*>(Br + kg * 8 + 4);
        float4 b2 = *reinterpret_cast<const float4*>(Br + 32 + kg * 8);
        float4 b3 = *reinterpret_cast<const float4*>(Br + 32 + kg * 8 + 4);
        float za[8] = {a0.x + b0.x, a0.y + b0.y, a0.z + b0.z, a0.w + b0.w,
                       a1.x + b1.x, a1.y + b1.y, a1.z + b1.z, a1.w + b1.w};
        float zb[8] = {a2.x + b2.x, a2.y + b2.y, a2.z + b2.z, a2.w + b2.w,
                       a3.x + b3.x, a3.y + b3.y, a3.z + b3.z, a3.w + b3.w};
        short8v aHi0, aLo0, aHi1, aLo1;
#pragma unroll
        for (int j = 0; j < 8; ++j) {
            float hv = fmaxf(za[j] - mpa[j], 0.f);
            unsigned short hi = bf16_hi(hv);
            aHi0[j] = (short)hi;
            aLo0[j] = (short)bf16_hi(hv - bf16_val(hi));
            float hv2 = fmaxf(zb[j] - mpb[j], 0.f);
            unsigned short hi2 = bf16_hi(hv2);
            aHi1[j] = (short)hi2;
            aLo1[j] = (short)bf16_hi(hv2 - bf16_val(hi2));
        }
        f32x4 acc[4];
#pragma unroll
        for (int ct = 0; ct < 4; ++ct) acc[ct] = (f32x4){0.f, 0.f, 0.f, 0.f};
#pragma unroll
        for (int ct = 0; ct < 4; ++ct) {
            acc[ct] = __builtin_amdgcn_mfma_f32_16x16x32_bf16(aHi0, Wf[ct][0], acc[ct], 0, 0, 0);
            acc[ct] = __builtin_amdgcn_mfma_f32_16x16x32_bf16(aLo0, Wf[ct][0], acc[ct], 0, 0, 0);
            acc[ct] = __builtin_amdgcn_mfma_f32_16x16x32_bf16(aHi1, Wf[ct][1], acc[ct], 0, 0, 0);
            acc[ct] = __builtin_amdgcn_mfma_f32_16x16x32_bf16(aLo1, Wf[ct][1], acc[ct], 0, 0, 0);
        }
        uint2* tz = zpk + (size_t)tile * 256 + kg * 16 + r16;
#pragma unroll
        for (int ct = 0; ct < 4; ++ct) {
            float z0 = acc[ct][0] + biasv[ct];
            float z1 = acc[ct][1] + biasv[ct];
            float z2 = acc[ct][2] + biasv[ct];
            float z3 = acc[ct][3] + biasv[ct];
            unsigned short u0 = bf16_rn(z0), u1 = bf16_rn(z1), u2 = bf16_rn(z2), u3 = bf16_rn(z3);
            float r0 = bf16_val(u0), r1 = bf16_val(u1), r2 = bf16_val(u2), r3 = bf16_val(u3);
            sum[ct] += (r0 + r1) + (r2 + r3);
            ssum[ct] += fmaf(r0, r0, fmaf(r1, r1, fmaf(r2, r2, r3 * r3)));
            uint2 pk;
            pk.x = (unsigned)u0 | ((unsigned)u1 << 16);
            pk.y = (unsigned)u2 | ((unsigned)u3 << 16);
            tz[ct * 64] = pk;
        }
    }
#pragma unroll
    for (int ct = 0; ct < 4; ++ct) {
        float s = sum[ct];
        s += __shfl_xor(s, 16);
        s += __shfl_xor(s, 32);
        float q = ssum[ct];
        q += __shfl_xor(q, 16);
        q += __shfl_xor(q, 32);
        if (kg == 0) {
            atomicAdd(&stats[128 + ct * 16 + r16], s);
            atomicAdd(&stats[192 + ct * 16 + r16], q);
        }
    }
}

// ---------------- fix: repair edge-affected rows (values + stats1 delta) ----------------
__global__ void __launch_bounds__(256) k_fix(const float* __restrict__ A, const float* __restrict__ Bm,
                                             const float* __restrict__ ewf,
                                             const int* __restrict__ boffs, const int* __restrict__ elist,
                                             const unsigned short* __restrict__ WT,
                                             const float* __restrict__ mprime, const float* __restrict__ L1b,
                                             unsigned int* __restrict__ zpk32, float* __restrict__ stats) {
    int lane = threadIdx.x & 63;
    int wid = blockIdx.x * 4 + (threadIdx.x >> 6);
    int nW = gridDim.x * 4;
    short8v wcolv[8];
#pragma unroll
    for (int q8 = 0; q8 < 8; ++q8)
        wcolv[q8] = *reinterpret_cast<const short8v*>(WT + lane * 64 + q8 * 8);
    float mp = mprime[lane];
    float bias = L1b[lane];
    float ds = 0.f, dss = 0.f;
    for (int t = wid; t < TT; t += nW) {
        int be = boffs[t], en = boffs[t + 1];
        if (be == en) continue;
        int g = t / TPG;
        int rem = t - g * TPG;
        int i = rem / 10;
        int j0 = (rem - i * 10) << 4;
        float a = A[(size_t)(g * NPG + i) * 64 + lane];
        unsigned pm = 0;
        for (int q = be; q < en; ++q) pm |= 1u << ((elist[q] & 15) >> 1);
        while (pm) {
            int pid = __ffs(pm) - 1;
            pm &= pm - 1;
            float S0 = 0.f, S1 = 0.f;
            bool aff0 = false, aff1 = false;
            for (int q = be; q < en; ++q) {
                int pk = elist[q];
                int jj = pk & 15;
                if ((jj >> 1) == pid) {
                    float ev = ewf[(size_t)(pk >> 4) * 64 + lane];
                    if (jj & 1) { S1 += ev; aff1 = true; }
                    else        { S0 += ev; aff0 = true; }
                }
            }
            int jb = g * NPG + j0 + 2 * pid;
            float z0e = a + Bm[(size_t)jb * 64 + lane];
            float z0o = a + Bm[(size_t)(jb + 1) * 64 + lane];
            float hec = fmaxf(z0e + S0 - mp, 0.f), hed = fmaxf(z0e - mp, 0.f);
            float hoc = fmaxf(z0o + S1 - mp, 0.f), hod = fmaxf(z0o - mp, 0.f);
            int bec_ = __float_as_int(hec), bed_ = __float_as_int(hed);
            int boc_ = __float_as_int(hoc), bod_ = __float_as_int(hod);
            float zec = bias, zed = bias, zoc = bias, zod = bias;
#pragma unroll
            for (int h = 0; h < 64; ++h) {
                float wv = bf16_val((unsigned short)wcolv[h >> 3][h & 7]);
                zec = fmaf(__int_as_float(__builtin_amdgcn_readlane(bec_, h)), wv, zec);
                zed = fmaf(__int_as_float(__builtin_amdgcn_readlane(bed_, h)), wv, zed);
                zoc = fmaf(__int_as_float(__builtin_amdgcn_readlane(boc_, h)), wv, zoc);
                zod = fmaf(__int_as_float(__builtin_amdgcn_readlane(bod_, h)), wv, zod);
            }
            size_t idx = (size_t)t * 512 + (size_t)(lane >> 4) * 128 + (size_t)(pid >> 1) * 32
                       + (size_t)(lane & 15) * 2 + (pid & 1);
            unsigned uold = zpk32[idx];
            unsigned short ue, uo;
            if (aff0) {
                ue = bf16_rn(zec);
                float zr = bf16_val(ue), zd = bf16_val(bf16_rn(zed));
                ds += zr - zd;
                dss += zr * zr - zd * zd;
            } else ue = (unsigned short)(uold & 0xffffu);
            if (aff1) {
                uo = bf16_rn(zoc);
                float zr = bf16_val(uo), zd = bf16_val(bf16_rn(zod));
                ds += zr - zd;
                dss += zr * zr - zd * zd;
            } else uo = (unsigned short)(uold >> 16);
            zpk32[idx] = (unsigned)ue | ((unsigned)uo << 16);
        }
    }
    __shared__ float ls[128];
    if (threadIdx.x < 128) ls[threadIdx.x] = 0.f;
    __syncthreads();
    atomicAdd(&ls[lane], ds);
    atomicAdd(&ls[64 + lane], dss);
    __syncthreads();
    if (threadIdx.x < 128) atomicAdd(&stats[128 + threadIdx.x], ls[threadIdx.x]);
}

// ---------------- final: out = relu(BN1(z1)) . L2w + L2b  (packed bf16 tile layout) ----------------
__global__ void __launch_bounds__(256) k_final(const float* __restrict__ g1, const float* __restrict__ beta1,
                                               const float* __restrict__ L2w, const float* __restrict__ L2b,
                                               const uint2* __restrict__ zpk, float* __restrict__ out,
                                               const float* __restrict__ stats) {
    int lane = threadIdx.x & 63;
    int wid = blockIdx.x * 4 + (threadIdx.x >> 6);
    int nW = gridDim.x * 4;
    int r16 = lane & 15, kg = lane >> 4;
    const float invP = 1.f / (float)PT;
    float s1c[4], t1c[4], wv[4];
#pragma unroll
    for (int ct = 0; ct < 4; ++ct) {
        int col = ct * 16 + r16;
        float mu = stats[128 + col] * invP;
        float var = stats[192 + col] * invP - mu * mu;
        float inv = rsqrtf(var + EPSB);
        s1c[ct] = g1[col] * inv;
        t1c[ct] = fmaf(-mu, s1c[ct], beta1[col]);
        wv[ct] = L2w[col];
    }
    float obias = L2b[0];
    for (int tile = wid; tile < TT; tile += nW) {
        const uint2* tz = zpk + (size_t)tile * 256 + kg * 16 + r16;
        uint2 cc0 = tz[0], cc1 = tz[64], cc2 = tz[128], cc3 = tz[192];
        float p0 = 0.f, p1 = 0.f, p2 = 0.f, p3 = 0.f;
        uint2 cc[4] = {cc0, cc1, cc2, cc3};
#pragma unroll
        for (int ct = 0; ct < 4; ++ct) {
            float z0 = bf16_val((unsigned short)(cc[ct].x & 0xffffu));
            float z1 = bf16_val((unsigned short)(cc[ct].x >> 16));
            float z2 = bf16_val((unsigned short)(cc[ct].y & 0xffffu));
            float z3 = bf16_val((unsigned short)(cc[ct].y >> 16));
            p0 = fmaf(fmaxf(fmaf(z0, s1c[ct], t1c[ct]), 0.f), wv[ct], p0);
            p1 = fmaf(fmaxf(fmaf(z1, s1c[ct], t1c[ct]), 0.f), wv[ct], p1);
            p2 = fmaf(fmaxf(fmaf(z2, s1c[ct], t1c[ct]), 0.f), wv[ct], p2);
            p3 = fmaf(fmaxf(fmaf(z3, s1c[ct], t1c[ct]), 0.f), wv[ct], p3);
        }
#pragma unroll
        for (int d = 1; d < 16; d <<= 1) {
            p0 += __shfl_xor(p0, d);
            p1 += __shfl_xor(p1, d);
            p2 += __shfl_xor(p2, d);
            p3 += __shfl_xor(p3, d);
        }
        if (r16 == 0) {
            float4 o = {p0 + obias, p1 + obias, p2 + obias, p3 + obias};
            *reinterpret_cast<float4*>(out + tile * 16 + kg * 4) = o;
        }
    }
}

extern "C" void kernel_launch(void* const* d_in, const int* in_sizes, int n_in,
                              void* d_out, int out_size, void* d_ws, size_t ws_size,
                              hipStream_t stream) {
    const float* atab  = (const float*)d_in[0];
    const float* btab  = (const float*)d_in[1];
    const float* W1    = (const float*)d_in[2];
    const float* b1    = (const float*)d_in[3];
    const float* W2    = (const float*)d_in[4];
    const float* b2    = (const float*)d_in[5];
    const float* We    = (const float*)d_in[6];
    const float* be    = (const float*)d_in[7];
    const float* L0w   = (const float*)d_in[8];
    const float* L0b   = (const float*)d_in[9];
    const float* L1w   = (const float*)d_in[10];
    const float* L1b   = (const float*)d_in[11];
    const float* L2w   = (const float*)d_in[12];
    const float* L2b   = (const float*)d_in[13];
    const float* g0    = (const float*)d_in[14];
    const float* beta0 = (const float*)d_in[15];
    const float* g1    = (const float*)d_in[16];
    const float* beta1 = (const float*)d_in[17];
    const int*   x     = (const int*)d_in[18];
    const int*   eattr = (const int*)d_in[19];
    // d_in[20], d_in[21] = idx0, idx1 (structured; computed arithmetically)
    const int*   epos  = (const int*)d_in[22];
    float* out = (float*)d_out;

    // workspace layout
    float* ws = (float*)d_ws;
    float* zpk_f = ws;                          // PT*64 bf16 = 13,107,200 floats (52.4 MB)
    float* A     = zpk_f + 13107200;            // 163,840
    float* Bm    = A + (size_t)NN * 64;         // 163,840
    float* ewf   = Bm + (size_t)NN * 64;        // 2,621,440
    float* W1c   = ewf + (size_t)EE * 64;       // 4096
    float* W2c   = W1c + 4096;
    float* Wec   = W2c + 4096;
    float* b1c   = Wec + 4096;                  // 64
    float* b2c   = b1c + 64;
    float* bec   = b2c + 64;
    float* stats = bec + 64;                    // 256
    float* mprime = stats + 256;                // 64
    unsigned short* WFRAG = (unsigned short*)(mprime + 64);  // 4096 ushort
    unsigned short* WT    = WFRAG + 4096;                    // 4096 ushort
    int* bcount  = (int*)(WT + 4096);           // TT
    int* boffs   = bcount + TT;                 // TT+1
    int* bcursor = boffs + TT + 1;              // TT
    int* elist   = bcursor + TT;                // EE

    uint2* zpk = (uint2*)zpk_f;
    unsigned int* zpk32 = (unsigned int*)zpk_f;

    hipMemsetAsync(stats, 0, 256 * sizeof(float), stream);
    hipMemsetAsync(bcount, 0, TT * sizeof(int), stream);

    k_prep<<<3, 256, 0, stream>>>(W1, b1, W2, b2, We, be, L0w, L0b,
                                  W1c, W2c, Wec, b1c, b2c, bec);
    k_nodes<<<NN, 64, 0, stream>>>(atab, x, W1c, W2c, b1c, b2c, A, Bm);
    k_gstats<<<NGr, 256, 0, stream>>>(A, Bm, stats);
    k_edges<<<512, 256, 0, stream>>>(btab, eattr, epos, Wec, bec, ewf, stats, bcount);
    k_scan<<<1, 256, 0, stream>>>(bcount, boffs, bcursor);
    k_fill<<<EE / 256, 256, 0, stream>>>(epos, bcursor, elist);
    k_scorr<<<256, 256, 0, stream>>>(A, Bm, ewf, boffs, elist, stats);
    k_wprep<<<1, 256, 0, stream>>>(L1w, g0, beta0, stats, mprime, WFRAG, WT);
    k_main<<<3200, 256, 0, stream>>>(WFRAG, mprime, L1b, A, Bm, zpk, stats);
    k_fix<<<1024, 256, 0, stream>>>(A, Bm, ewf, boffs, elist, WT, mprime, L1b, zpk32, stats);
    k_final<<<2048, 256, 0, stream>>>(g1, beta1, L2w, L2b, zpk, out, stats);
}

// Round 6
// 329.967 us; speedup vs baseline: 1.9078x; 1.9078x over previous
//
#include <hip/hip_runtime.h>
#include <hip/hip_bf16.h>

#define HID 64
#define NGr 16
#define NPG 160
#define NN  2560            // NGr*NPG
#define EE  40960
#define PPG 25600           // NPG*NPG
#define PT  409600          // NGr*PPG
#define AV  64
#define BV  8
#define EPSB 1e-5f

typedef __attribute__((ext_vector_type(8))) short short8v;   // 8 bf16 (4 VGPRs)
typedef __attribute__((ext_vector_type(4))) float f32x4;

static __device__ __forceinline__ unsigned short bf16_hi(float v) {
    return (unsigned short)(__float_as_uint(v) >> 16);
}
static __device__ __forceinline__ float bf16_val(unsigned short h) {
    return __uint_as_float(((unsigned int)h) << 16);
}

// ---------------- prep: combined weights + zero stats + bf16-split L1w ----------------
__global__ void k_prep(const float* __restrict__ W1, const float* __restrict__ b1,
                       const float* __restrict__ W2, const float* __restrict__ b2,
                       const float* __restrict__ We, const float* __restrict__ be,
                       const float* __restrict__ L0w, const float* __restrict__ L0b,
                       const float* __restrict__ L1w,
                       float* __restrict__ W1c, float* __restrict__ W2c, float* __restrict__ Wec,
                       float* __restrict__ b1c, float* __restrict__ b2c, float* __restrict__ bec,
                       float* __restrict__ stats,
                       unsigned short* __restrict__ WBhi, unsigned short* __restrict__ WBlo) {
    int blk = blockIdx.x, tid = threadIdx.x;
    if (blk == 3) {
        stats[tid] = 0.f;                 // 256 threads zero 256 stat floats
        for (int idx = tid; idx < 4096; idx += 256) {
            float w = L1w[idx];
            unsigned short hi = bf16_hi(w);
            float rem = w - bf16_val(hi);
            WBhi[idx] = hi;
            WBlo[idx] = bf16_hi(rem);
        }
        return;
    }
    const float* Wsrc = (blk == 0) ? W1 : (blk == 1) ? W2 : We;
    const float* bsrc = (blk == 0) ? b1 : (blk == 1) ? b2 : be;
    const float* L    = L0w + blk * 64 * 64;
    float* Wdst = (blk == 0) ? W1c : (blk == 1) ? W2c : Wec;
    float* bdst = (blk == 0) ? b1c : (blk == 1) ? b2c : bec;
    for (int idx = tid; idx < 4096; idx += 256) {
        int k = idx >> 6, h = idx & 63;
        float acc = 0.f;
        for (int m = 0; m < 64; ++m) acc = fmaf(Wsrc[k * 64 + m], L[m * 64 + h], acc);
        Wdst[idx] = acc;
    }
    if (tid < 64) {
        int h = tid;
        float acc = (blk == 0) ? L0b[h] : 0.f;
        for (int m = 0; m < 64; ++m) acc = fmaf(bsrc[m], L[m * 64 + h], acc);
        bdst[h] = acc;
    }
}

// ---------------- nodes: x_emb -> A, B (2560 x 64 each) ----------------
__global__ void k_nodes(const float* __restrict__ atab, const int* __restrict__ x,
                        const float* __restrict__ W1c, const float* __restrict__ W2c,
                        const float* __restrict__ b1c, const float* __restrict__ b2c,
                        float* __restrict__ A, float* __restrict__ Bm) {
    int n = blockIdx.x, h = threadIdx.x;
    __shared__ float xe[64];
    float v = 0.f;
#pragma unroll
    for (int c = 0; c < 9; ++c) v += atab[c * AV * HID + x[n * 9 + c] * HID + h];
    xe[h] = v;
    __syncthreads();
    float a = b1c[h], b = b2c[h];
#pragma unroll
    for (int k = 0; k < 64; ++k) {
        float xk = xe[k];
        a = fmaf(xk, W1c[k * 64 + h], a);
        b = fmaf(xk, W2c[k * 64 + h], b);
    }
    A[n * 64 + h] = a;
    Bm[n * 64 + h] = b;
}

// ---------------- dense fill: z0 = A[i] + B[j], fused BN0 stats ----------------
__global__ void __launch_bounds__(256) k_dense(const float* __restrict__ A, const float* __restrict__ Bm,
                                               float* __restrict__ zbuf, float* __restrict__ stats) {
    int h = threadIdx.x & 63;
    int wid = threadIdx.x >> 6;
    int wavesTotal = gridDim.x * 4;
    int wave = blockIdx.x * 4 + wid;
    float s = 0.f, ss = 0.f;
    for (int row = wave; row < PT; row += wavesTotal) {
        int g = row / PPG;
        int rem = row - g * PPG;
        int i = rem / NPG;
        int j = rem - i * NPG;
        float v = A[(g * NPG + i) * 64 + h] + Bm[(g * NPG + j) * 64 + h];
        zbuf[(size_t)row * 64 + h] = v;
        s += v;
        ss = fmaf(v, v, ss);
    }
    __shared__ float ls[128];
    if (threadIdx.x < 128) ls[threadIdx.x] = 0.f;
    __syncthreads();
    atomicAdd(&ls[h], s);
    atomicAdd(&ls[64 + h], ss);
    __syncthreads();
    if (threadIdx.x < 128) atomicAdd(&stats[threadIdx.x], ls[threadIdx.x]);
}

// ---------------- edges: Ew = (bond_emb @ Wec + bec); scatter into z0; exact stats fix ----------------
__global__ void __launch_bounds__(256) k_edges(const float* __restrict__ btab, const int* __restrict__ eattr,
                                               const int* __restrict__ epos,
                                               const float* __restrict__ Wec, const float* __restrict__ bec,
                                               float* __restrict__ zbuf, float* __restrict__ stats) {
    int h = threadIdx.x & 63;
    int el = threadIdx.x >> 6;          // wave id = edge slot
    __shared__ float ea[4][64];
    float s = 0.f, ss = 0.f;
    for (int base = blockIdx.x * 4; base < EE; base += gridDim.x * 4) {
        int e = base + el;
        float v = 0.f;
#pragma unroll
        for (int c = 0; c < 3; ++c) v += btab[c * BV * HID + eattr[e * 3 + c] * HID + h];
        ea[el][h] = v;
        __syncthreads();
        float ew = bec[h];
#pragma unroll
        for (int k = 0; k < 64; ++k) ew = fmaf(ea[el][k], Wec[k * 64 + h], ew);
        int p = epos[e];
        float old = atomicAdd(&zbuf[(size_t)p * 64 + h], ew);
        s += ew;
        ss += 2.f * old * ew + ew * ew;   // (old+ew)^2 - old^2, exact under any atomic order
        __syncthreads();
    }
    __shared__ float ls[128];
    if (threadIdx.x < 128) ls[threadIdx.x] = 0.f;
    __syncthreads();
    atomicAdd(&ls[h], s);
    atomicAdd(&ls[64 + h], ss);
    __syncthreads();
    if (threadIdx.x < 128) atomicAdd(&stats[threadIdx.x], ls[threadIdx.x]);
}

// ---------------- mid (MFMA): h0 = relu(BN0(z0)); z1 = h0 @ L1 + b1 (in place); BN1 stats ----------------
// bf16 hi/lo split: z1 = hHi@wHi + hHi@wLo + hLo@wHi  (err ~2^-17 rel)
// A-frag: lane l -> row (l&15), k = (l>>4)*8 + j  (j=0..7), per K-step of 32
// B-frag: lane l -> k = (l>>4)*8 + j, col (l&15)
// D:      lane l -> col (l&15), row (l>>4)*4 + reg
__global__ void __launch_bounds__(256) k_mid(const unsigned short* __restrict__ WBhi,
                                             const unsigned short* __restrict__ WBlo,
                                             const float* __restrict__ L1b,
                                             const float* __restrict__ g0, const float* __restrict__ beta0,
                                             float* __restrict__ zbuf, float* __restrict__ stats) {
    int lane = threadIdx.x & 63;
    int wid  = blockIdx.x * 4 + (threadIdx.x >> 6);
    int nWaves = gridDim.x * 4;
    int r16 = lane & 15;
    int kg  = lane >> 4;

    const float invP = 1.f / (float)PT;
    // BN0 coeffs for this lane's k-columns (two K-halves)
    float s0a[8], t0a[8], s0b[8], t0b[8];
#pragma unroll
    for (int j = 0; j < 8; ++j) {
        int k = kg * 8 + j;
        float mu = stats[k] * invP;
        float var = stats[64 + k] * invP - mu * mu;
        float inv = rsqrtf(var + EPSB);
        s0a[j] = g0[k] * inv;
        t0a[j] = fmaf(-mu, s0a[j], beta0[k]);
        int k2 = k + 32;
        float mu2 = stats[k2] * invP;
        float var2 = stats[64 + k2] * invP - mu2 * mu2;
        float inv2 = rsqrtf(var2 + EPSB);
        s0b[j] = g0[k2] * inv2;
        t0b[j] = fmaf(-mu2, s0b[j], beta0[k2]);
    }
    // B fragments (weights), loaded once per wave: [col-tile][K-step]
    short8v Bhi[4][2], Blo[4][2];
#pragma unroll
    for (int ct = 0; ct < 4; ++ct)
#pragma unroll
        for (int ks = 0; ks < 2; ++ks)
#pragma unroll
            for (int j = 0; j < 8; ++j) {
                int k = ks * 32 + kg * 8 + j;
                int idx = k * 64 + ct * 16 + r16;
                Bhi[ct][ks][j] = (short)WBhi[idx];
                Blo[ct][ks][j] = (short)WBlo[idx];
            }
    float biasv[4];
#pragma unroll
    for (int ct = 0; ct < 4; ++ct) biasv[ct] = L1b[ct * 16 + r16];

    float sum[4] = {0.f, 0.f, 0.f, 0.f}, ssum[4] = {0.f, 0.f, 0.f, 0.f};

    for (int tile = wid; tile < PT / 16; tile += nWaves) {
        float* tb = zbuf + (size_t)tile * 16 * 64;
        const float4 za0 = *reinterpret_cast<const float4*>(tb + r16 * 64 + kg * 8);
        const float4 za1 = *reinterpret_cast<const float4*>(tb + r16 * 64 + kg * 8 + 4);
        const float4 zb0 = *reinterpret_cast<const float4*>(tb + r16 * 64 + 32 + kg * 8);
        const float4 zb1 = *reinterpret_cast<const float4*>(tb + r16 * 64 + 32 + kg * 8 + 4);
        float ha[8] = {za0.x, za0.y, za0.z, za0.w, za1.x, za1.y, za1.z, za1.w};
        float hb[8] = {zb0.x, zb0.y, zb0.z, zb0.w, zb1.x, zb1.y, zb1.z, zb1.w};
        short8v aHi0, aLo0, aHi1, aLo1;
#pragma unroll
        for (int j = 0; j < 8; ++j) {
            float hv = fmaxf(fmaf(ha[j], s0a[j], t0a[j]), 0.f);
            unsigned short hi = bf16_hi(hv);
            float rem = hv - bf16_val(hi);
            aHi0[j] = (short)hi;
            aLo0[j] = (short)bf16_hi(rem);
            float hv2 = fmaxf(fmaf(hb[j], s0b[j], t0b[j]), 0.f);
            unsigned short hi2 = bf16_hi(hv2);
            float rem2 = hv2 - bf16_val(hi2);
            aHi1[j] = (short)hi2;
            aLo1[j] = (short)bf16_hi(rem2);
        }
        f32x4 acc[4];
#pragma unroll
        for (int ct = 0; ct < 4; ++ct) acc[ct] = (f32x4){0.f, 0.f, 0.f, 0.f};
#pragma unroll
        for (int ct = 0; ct < 4; ++ct) {
            acc[ct] = __builtin_amdgcn_mfma_f32_16x16x32_bf16(aHi0, Bhi[ct][0], acc[ct], 0, 0, 0);
            acc[ct] = __builtin_amdgcn_mfma_f32_16x16x32_bf16(aHi0, Blo[ct][0], acc[ct], 0, 0, 0);
            acc[ct] = __builtin_amdgcn_mfma_f32_16x16x32_bf16(aLo0, Bhi[ct][0], acc[ct], 0, 0, 0);
            acc[ct] = __builtin_amdgcn_mfma_f32_16x16x32_bf16(aHi1, Bhi[ct][1], acc[ct], 0, 0, 0);
            acc[ct] = __builtin_amdgcn_mfma_f32_16x16x32_bf16(aHi1, Blo[ct][1], acc[ct], 0, 0, 0);
            acc[ct] = __builtin_amdgcn_mfma_f32_16x16x32_bf16(aLo1, Bhi[ct][1], acc[ct], 0, 0, 0);
        }
        // epilogue: D lane -> col r16, row kg*4+reg (f32 dword stores — proven fast)
#pragma unroll
        for (int ct = 0; ct < 4; ++ct) {
#pragma unroll
            for (int reg = 0; reg < 4; ++reg) {
                float z = acc[ct][reg] + biasv[ct];
                tb[(kg * 4 + reg) * 64 + ct * 16 + r16] = z;
                sum[ct] += z;
                ssum[ct] = fmaf(z, z, ssum[ct]);
            }
        }
    }
    // reduce stats across lanes sharing a column (xor 16, 32), then atomics from kg==0
#pragma unroll
    for (int ct = 0; ct < 4; ++ct) {
        float s = sum[ct];
        s += __shfl_xor(s, 16);
        s += __shfl_xor(s, 32);
        float q = ssum[ct];
        q += __shfl_xor(q, 16);
        q += __shfl_xor(q, 32);
        if (kg == 0) {
            atomicAdd(&stats[128 + ct * 16 + r16], s);
            atomicAdd(&stats[192 + ct * 16 + r16], q);
        }
    }
}

// ---------------- final: out = relu(BN1(z1)) . L2w + L2b ----------------
__global__ void __launch_bounds__(256) k_final(const float* __restrict__ g1, const float* __restrict__ beta1,
                                               const float* __restrict__ L2w, const float* __restrict__ L2b,
                                               const float* __restrict__ zbuf, float* __restrict__ out,
                                               const float* __restrict__ stats) {
    int lane = threadIdx.x & 63;
    int wid = threadIdx.x >> 6;
    int q = lane & 15;     // quad within row
    int rl = lane >> 4;    // row within group of 4
    const float invP = 1.f / (float)PT;
    float s1[4], t1[4], wv[4];
#pragma unroll
    for (int c = 0; c < 4; ++c) {
        int col = q * 4 + c;
        float mu = stats[128 + col] * invP;
        float var = stats[192 + col] * invP - mu * mu;
        float inv = rsqrtf(var + EPSB);
        s1[c] = g1[col] * inv;
        t1[c] = fmaf(-mu, s1[c], beta1[col]);
        wv[c] = L2w[col];
    }
    float bias = L2b[0];
    int waveId = blockIdx.x * 4 + wid;
    int stride = gridDim.x * 16;
    for (int base = waveId * 4; base < PT; base += stride) {
        const float4 zv = *reinterpret_cast<const float4*>(zbuf + (size_t)base * 64 + lane * 4);
        float p;
        p  = fmaxf(fmaf(zv.x, s1[0], t1[0]), 0.f) * wv[0];
        p  = fmaf(fmaxf(fmaf(zv.y, s1[1], t1[1]), 0.f), wv[1], p);
        p  = fmaf(fmaxf(fmaf(zv.z, s1[2], t1[2]), 0.f), wv[2], p);
        p  = fmaf(fmaxf(fmaf(zv.w, s1[3], t1[3]), 0.f), wv[3], p);
        p += __shfl_xor(p, 1);
        p += __shfl_xor(p, 2);
        p += __shfl_xor(p, 4);
        p += __shfl_xor(p, 8);
        if (q == 0) out[base + rl] = p + bias;
    }
}

extern "C" void kernel_launch(void* const* d_in, const int* in_sizes, int n_in,
                              void* d_out, int out_size, void* d_ws, size_t ws_size,
                              hipStream_t stream) {
    const float* atab  = (const float*)d_in[0];
    const float* btab  = (const float*)d_in[1];
    const float* W1    = (const float*)d_in[2];
    const float* b1    = (const float*)d_in[3];
    const float* W2    = (const float*)d_in[4];
    const float* b2    = (const float*)d_in[5];
    const float* We    = (const float*)d_in[6];
    const float* be    = (const float*)d_in[7];
    const float* L0w   = (const float*)d_in[8];
    const float* L0b   = (const float*)d_in[9];
    const float* L1w   = (const float*)d_in[10];
    const float* L1b   = (const float*)d_in[11];
    const float* L2w   = (const float*)d_in[12];
    const float* L2b   = (const float*)d_in[13];
    const float* g0    = (const float*)d_in[14];
    const float* beta0 = (const float*)d_in[15];
    const float* g1    = (const float*)d_in[16];
    const float* beta1 = (const float*)d_in[17];
    const int*   x     = (const int*)d_in[18];
    const int*   eattr = (const int*)d_in[19];
    // d_in[20], d_in[21] = idx0, idx1 (structured; computed arithmetically)
    const int*   epos  = (const int*)d_in[22];
    float* out = (float*)d_out;

    // workspace layout (floats)
    float* ws = (float*)d_ws;
    float* zbuf = ws;                       // PT*64 = 26,214,400
    float* A    = zbuf + (size_t)PT * 64;   // 163,840
    float* Bm   = A + NN * 64;              // 163,840
    float* W1c  = Bm + NN * 64;             // 4096
    float* W2c  = W1c + 4096;               // 4096
    float* Wec  = W2c + 4096;               // 4096
    float* b1c  = Wec + 4096;               // 64
    float* b2c  = b1c + 64;                 // 64
    float* bec  = b2c + 64;                 // 64
    float* stats = bec + 64;                // 256: sum0,ss0,sum1,ss1
    unsigned short* WBhi = (unsigned short*)(stats + 256);  // 4096 ushort
    unsigned short* WBlo = WBhi + 4096;                     // 4096 ushort

    k_prep<<<4, 256, 0, stream>>>(W1, b1, W2, b2, We, be, L0w, L0b, L1w,
                                  W1c, W2c, Wec, b1c, b2c, bec, stats, WBhi, WBlo);
    k_nodes<<<NN, 64, 0, stream>>>(atab, x, W1c, W2c, b1c, b2c, A, Bm);
    k_dense<<<2048, 256, 0, stream>>>(A, Bm, zbuf, stats);
    k_edges<<<1024, 256, 0, stream>>>(btab, eattr, epos, Wec, bec, zbuf, stats);
    k_mid<<<1600, 256, 0, stream>>>(WBhi, WBlo, L1b, g0, beta0, zbuf, stats);
    k_final<<<2048, 256, 0, stream>>>(g1, beta1, L2w, L2b, zbuf, out, stats);
}

// Round 7
// 296.249 us; speedup vs baseline: 2.1249x; 1.1138x over previous
//
#include <hip/hip_runtime.h>
#include <hip/hip_bf16.h>

#define HID 64
#define NGr 16
#define NPG 160
#define NN  2560            // NGr*NPG
#define EE  40960
#define PPG 25600           // NPG*NPG
#define PT  409600          // NGr*PPG
#define TT  25600           // PT/16 tiles (16 pairs each)
#define TPG 1600            // tiles per graph
#define AV  64
#define BV  8
#define EPSB 1e-5f

typedef __attribute__((ext_vector_type(8))) short short8v;   // 8 bf16 (4 VGPRs)
typedef __attribute__((ext_vector_type(4))) float f32x4;

static __device__ __forceinline__ unsigned short bf16_hi(float v) {   // truncate
    return (unsigned short)(__float_as_uint(v) >> 16);
}
static __device__ __forceinline__ float bf16_val(unsigned short h) {
    return __uint_as_float(((unsigned int)h) << 16);
}

// ---------------- prep: combined weights + zero stats + bf16-split L1w ----------------
__global__ void k_prep(const float* __restrict__ W1, const float* __restrict__ b1,
                       const float* __restrict__ W2, const float* __restrict__ b2,
                       const float* __restrict__ We, const float* __restrict__ be,
                       const float* __restrict__ L0w, const float* __restrict__ L0b,
                       const float* __restrict__ L1w,
                       float* __restrict__ W1c, float* __restrict__ W2c, float* __restrict__ Wec,
                       float* __restrict__ b1c, float* __restrict__ b2c, float* __restrict__ bec,
                       float* __restrict__ stats,
                       unsigned short* __restrict__ WBhi, unsigned short* __restrict__ WBlo) {
    int blk = blockIdx.x, tid = threadIdx.x;
    if (blk == 3) {
        stats[tid] = 0.f;                 // 256 threads zero 256 stat floats
        for (int idx = tid; idx < 4096; idx += 256) {
            float w = L1w[idx];
            unsigned short hi = bf16_hi(w);
            float rem = w - bf16_val(hi);
            WBhi[idx] = hi;
            WBlo[idx] = bf16_hi(rem);
        }
        return;
    }
    const float* Wsrc = (blk == 0) ? W1 : (blk == 1) ? W2 : We;
    const float* bsrc = (blk == 0) ? b1 : (blk == 1) ? b2 : be;
    const float* L    = L0w + blk * 64 * 64;
    float* Wdst = (blk == 0) ? W1c : (blk == 1) ? W2c : Wec;
    float* bdst = (blk == 0) ? b1c : (blk == 1) ? b2c : bec;
    for (int idx = tid; idx < 4096; idx += 256) {
        int k = idx >> 6, h = idx & 63;
        float acc = 0.f;
        for (int m = 0; m < 64; ++m) acc = fmaf(Wsrc[k * 64 + m], L[m * 64 + h], acc);
        Wdst[idx] = acc;
    }
    if (tid < 64) {
        int h = tid;
        float acc = (blk == 0) ? L0b[h] : 0.f;
        for (int m = 0; m < 64; ++m) acc = fmaf(bsrc[m], L[m * 64 + h], acc);
        bdst[h] = acc;
    }
}

// ---------------- nodes: x_emb -> A, B (2560 x 64 each) ----------------
__global__ void k_nodes(const float* __restrict__ atab, const int* __restrict__ x,
                        const float* __restrict__ W1c, const float* __restrict__ W2c,
                        const float* __restrict__ b1c, const float* __restrict__ b2c,
                        float* __restrict__ A, float* __restrict__ Bm) {
    int n = blockIdx.x, h = threadIdx.x;
    __shared__ float xe[64];
    float v = 0.f;
#pragma unroll
    for (int c = 0; c < 9; ++c) v += atab[c * AV * HID + x[n * 9 + c] * HID + h];
    xe[h] = v;
    __syncthreads();
    float a = b1c[h], b = b2c[h];
#pragma unroll
    for (int k = 0; k < 64; ++k) {
        float xk = xe[k];
        a = fmaf(xk, W1c[k * 64 + h], a);
        b = fmaf(xk, W2c[k * 64 + h], b);
    }
    A[n * 64 + h] = a;
    Bm[n * 64 + h] = b;
}

// ---------------- gstats: analytic BN0 stats from A,B (dense part) ----------------
// sum0 += 160*(SumA + SumB);  ss0 += 160*(SumA2 + SumB2) + 2*SumA*SumB   (per graph, per h)
__global__ void k_gstats(const float* __restrict__ A, const float* __restrict__ Bm,
                         float* __restrict__ stats) {
    int g = blockIdx.x;
    int h = threadIdx.x & 63, w = threadIdx.x >> 6;
    float sA = 0.f, sA2 = 0.f, sB = 0.f, sB2 = 0.f;
    for (int n = w; n < NPG; n += 4) {
        float a = A[(size_t)(g * NPG + n) * 64 + h];
        float b = Bm[(size_t)(g * NPG + n) * 64 + h];
        sA += a; sA2 = fmaf(a, a, sA2);
        sB += b; sB2 = fmaf(b, b, sB2);
    }
    __shared__ float ls[4][4][64];
    ls[w][0][h] = sA; ls[w][1][h] = sA2; ls[w][2][h] = sB; ls[w][3][h] = sB2;
    __syncthreads();
    if (w == 0) {
        sA  = ls[0][0][h] + ls[1][0][h] + ls[2][0][h] + ls[3][0][h];
        sA2 = ls[0][1][h] + ls[1][1][h] + ls[2][1][h] + ls[3][1][h];
        sB  = ls[0][2][h] + ls[1][2][h] + ls[2][2][h] + ls[3][2][h];
        sB2 = ls[0][3][h] + ls[1][3][h] + ls[2][3][h] + ls[3][3][h];
        atomicAdd(&stats[h], 160.f * (sA + sB));
        atomicAdd(&stats[64 + h], 160.f * (sA2 + sB2) + 2.f * sA * sB);
    }
}

// ---------------- edges: ew = bond_emb @ Wec + bec -> ewf; sum0 += ew; bucket counts ----------------
__global__ void __launch_bounds__(256) k_edges(const float* __restrict__ btab, const int* __restrict__ eattr,
                                               const int* __restrict__ epos,
                                               const float* __restrict__ Wec, const float* __restrict__ bec,
                                               float* __restrict__ ewf, float* __restrict__ stats,
                                               int* __restrict__ bcount) {
    int h = threadIdx.x & 63;
    int el = threadIdx.x >> 6;
    __shared__ float ea[4][64];
    float ssum = 0.f;
    for (int base = blockIdx.x * 4; base < EE; base += gridDim.x * 4) {
        int e = base + el;
        float v = 0.f;
#pragma unroll
        for (int c = 0; c < 3; ++c) v += btab[c * BV * HID + eattr[e * 3 + c] * HID + h];
        ea[el][h] = v;                   // wave-local, wave-synchronous
        float ew = bec[h];
#pragma unroll
        for (int k = 0; k < 64; ++k) ew = fmaf(ea[el][k], Wec[k * 64 + h], ew);
        ewf[(size_t)e * 64 + h] = ew;
        ssum += ew;
        if (h == 0) atomicAdd(&bcount[epos[e] >> 4], 1);
    }
    atomicAdd(&stats[h], ssum);
}

// ---------------- scan: exclusive prefix of bcount[TT] -> boffs, bcursor ----------------
__global__ void k_scan(const int* __restrict__ bcount, int* __restrict__ boffs,
                       int* __restrict__ bcursor) {
    __shared__ int part[256];
    int tid = threadIdx.x;
    int base = tid * (TT / 256);
    int s = 0;
    for (int q = 0; q < TT / 256; ++q) s += bcount[base + q];
    part[tid] = s;
    __syncthreads();
    for (int d = 1; d < 256; d <<= 1) {
        int v = (tid >= d) ? part[tid - d] : 0;
        __syncthreads();
        part[tid] += v;
        __syncthreads();
    }
    int run = part[tid] - s;   // exclusive prefix
    for (int q = 0; q < TT / 256; ++q) {
        int c = bcount[base + q];
        boffs[base + q] = run;
        bcursor[base + q] = run;
        run += c;
    }
    if (tid == 255) boffs[TT] = run;
}

// ---------------- fill: elist[slot] = (e<<4) | jslot ----------------
__global__ void k_fill(const int* __restrict__ epos, int* __restrict__ bcursor,
                       int* __restrict__ elist) {
    int e = blockIdx.x * 256 + threadIdx.x;
    if (e >= EE) return;
    int p = epos[e];
    int t = p >> 4, jj = p & 15;
    int slot = atomicAdd(&bcursor[t], 1);
    elist[slot] = (e << 4) | jj;
}

// ---------------- scorr: sparse ss0 correction ----------------
// telescoped per-edge: 2*(base + runsum)*ew + ew^2, any order within bucket
__global__ void __launch_bounds__(256) k_scorr(const float* __restrict__ A, const float* __restrict__ Bm,
                                               const float* __restrict__ ewf,
                                               const int* __restrict__ boffs, const int* __restrict__ elist,
                                               float* __restrict__ stats) {
    __shared__ float run[4][16][64];
    int h = threadIdx.x & 63, w = threadIdx.x >> 6;
#pragma unroll
    for (int jj = 0; jj < 16; ++jj) run[w][jj][h] = 0.f;
    float ssacc = 0.f;
    int wave = blockIdx.x * 4 + w;
    int nw = gridDim.x * 4;
    for (int t = wave; t < TT; t += nw) {
        int be = boffs[t], en = boffs[t + 1];
        if (be == en) continue;
        int g = t / TPG;
        int rem = t - g * TPG;
        int i = rem / 10;
        int j0 = (rem - i * 10) << 4;
        float a = A[(size_t)(g * NPG + i) * 64 + h];
        for (int q = be; q < en; ++q) {
            int pk = elist[q];
            int e = pk >> 4, jj = pk & 15;
            float ew = ewf[(size_t)e * 64 + h];
            float base = a + Bm[(size_t)(g * NPG + j0 + jj) * 64 + h];
            float r = run[w][jj][h];
            ssacc += 2.f * (base + r) * ew + ew * ew;
            run[w][jj][h] = r + ew;
        }
        for (int q = be; q < en; ++q) run[w][elist[q] & 15][h] = 0.f;
    }
    atomicAdd(&stats[64 + h], ssacc);
}

// ---------------- main (fused dense+edges+mid): z0 in regs -> BN0 -> relu -> MFMA -> z1 (f32) + stats1 ----
// A-frag: lane l -> row (l&15)=pair, k=(l>>4)*8+j per K-half; D: col=l&15, row=(l>>4)*4+reg
// Grid MUST stay small (512): this family is prologue-amortization-bound; 1600+ blocks measured 2.2x slower.
__global__ void __launch_bounds__(256) k_main(const unsigned short* __restrict__ WBhi,
                                              const unsigned short* __restrict__ WBlo,
                                              const float* __restrict__ L1b,
                                              const float* __restrict__ g0, const float* __restrict__ beta0,
                                              const float* __restrict__ A, const float* __restrict__ Bm,
                                              const float* __restrict__ ewf,
                                              const int* __restrict__ boffs, const int* __restrict__ elist,
                                              float* __restrict__ zbuf, float* __restrict__ stats) {
    int lane = threadIdx.x & 63;
    int wid  = blockIdx.x * 4 + (threadIdx.x >> 6);
    int nWaves = gridDim.x * 4;
    int r16 = lane & 15;
    int kg  = lane >> 4;

    const float invP = 1.f / (float)PT;
    float s0a[8], t0a[8], s0b[8], t0b[8];
#pragma unroll
    for (int j = 0; j < 8; ++j) {
        int k = kg * 8 + j;
        float mu = stats[k] * invP;
        float var = stats[64 + k] * invP - mu * mu;
        float inv = rsqrtf(var + EPSB);
        s0a[j] = g0[k] * inv;
        t0a[j] = fmaf(-mu, s0a[j], beta0[k]);
        int k2 = k + 32;
        float mu2 = stats[k2] * invP;
        float var2 = stats[64 + k2] * invP - mu2 * mu2;
        float inv2 = rsqrtf(var2 + EPSB);
        s0b[j] = g0[k2] * inv2;
        t0b[j] = fmaf(-mu2, s0b[j], beta0[k2]);
    }
    // B fragments (weights), loaded once per wave: [col-tile][K-step]
    short8v Bhi[4][2], Blo[4][2];
#pragma unroll
    for (int ct = 0; ct < 4; ++ct)
#pragma unroll
        for (int ks = 0; ks < 2; ++ks)
#pragma unroll
            for (int j = 0; j < 8; ++j) {
                int k = ks * 32 + kg * 8 + j;
                int idx = k * 64 + ct * 16 + r16;
                Bhi[ct][ks][j] = (short)WBhi[idx];
                Blo[ct][ks][j] = (short)WBlo[idx];
            }
    float biasv[4];
#pragma unroll
    for (int ct = 0; ct < 4; ++ct) biasv[ct] = L1b[ct * 16 + r16];

    float sum[4] = {0.f, 0.f, 0.f, 0.f}, ssum[4] = {0.f, 0.f, 0.f, 0.f};

    for (int tile = wid; tile < TT; tile += nWaves) {
        // rebuild z0 in registers: z0[pair r16][k] = A[i][k] + B[j0+r16][k] (+ edge rows)
        int g = tile / TPG;
        int rem = tile - g * TPG;
        int i = rem / 10;
        int j0 = (rem - i * 10) << 4;
        const float* Ar = A + (size_t)(g * NPG + i) * 64;
        const float* Br = Bm + (size_t)(g * NPG + j0 + r16) * 64;
        float4 a0 = *reinterpret_cast<const float4*>(Ar + kg * 8);
        float4 a1 = *reinterpret_cast<const float4*>(Ar + kg * 8 + 4);
        float4 a2 = *reinterpret_cast<const float4*>(Ar + 32 + kg * 8);
        float4 a3 = *reinterpret_cast<const float4*>(Ar + 32 + kg * 8 + 4);
        float4 b0 = *reinterpret_cast<const float4*>(Br + kg * 8);
        float4 b1 = *reinterpret_cast<const float4*>(Br + kg * 8 + 4);
        float4 b2 = *reinterpret_cast<const float4*>(Br + 32 + kg * 8);
        float4 b3 = *reinterpret_cast<const float4*>(Br + 32 + kg * 8 + 4);
        float ha[8] = {a0.x + b0.x, a0.y + b0.y, a0.z + b0.z, a0.w + b0.w,
                       a1.x + b1.x, a1.y + b1.y, a1.z + b1.z, a1.w + b1.w};
        float hb[8] = {a2.x + b2.x, a2.y + b2.y, a2.z + b2.z, a2.w + b2.w,
                       a3.x + b3.x, a3.y + b3.y, a3.z + b3.z, a3.w + b3.w};
        int be = boffs[tile], en = boffs[tile + 1];
        for (int q = be; q < en; ++q) {
            int pk = elist[q];
            if (r16 == (pk & 15)) {
                const float* er = ewf + (size_t)(pk >> 4) * 64;
                float4 e0 = *reinterpret_cast<const float4*>(er + kg * 8);
                float4 e1 = *reinterpret_cast<const float4*>(er + kg * 8 + 4);
                float4 e2 = *reinterpret_cast<const float4*>(er + 32 + kg * 8);
                float4 e3 = *reinterpret_cast<const float4*>(er + 32 + kg * 8 + 4);
                ha[0] += e0.x; ha[1] += e0.y; ha[2] += e0.z; ha[3] += e0.w;
                ha[4] += e1.x; ha[5] += e1.y; ha[6] += e1.z; ha[7] += e1.w;
                hb[0] += e2.x; hb[1] += e2.y; hb[2] += e2.z; hb[3] += e2.w;
                hb[4] += e3.x; hb[5] += e3.y; hb[6] += e3.z; hb[7] += e3.w;
            }
        }
        short8v aHi0, aLo0, aHi1, aLo1;
#pragma unroll
        for (int j = 0; j < 8; ++j) {
            float hv = fmaxf(fmaf(ha[j], s0a[j], t0a[j]), 0.f);
            unsigned short hi = bf16_hi(hv);
            float remv = hv - bf16_val(hi);
            aHi0[j] = (short)hi;
            aLo0[j] = (short)bf16_hi(remv);
            float hv2 = fmaxf(fmaf(hb[j], s0b[j], t0b[j]), 0.f);
            unsigned short hi2 = bf16_hi(hv2);
            float rem2 = hv2 - bf16_val(hi2);
            aHi1[j] = (short)hi2;
            aLo1[j] = (short)bf16_hi(rem2);
        }
        f32x4 acc[4];
#pragma unroll
        for (int ct = 0; ct < 4; ++ct) acc[ct] = (f32x4){0.f, 0.f, 0.f, 0.f};
#pragma unroll
        for (int ct = 0; ct < 4; ++ct) {
            acc[ct] = __builtin_amdgcn_mfma_f32_16x16x32_bf16(aHi0, Bhi[ct][0], acc[ct], 0, 0, 0);
            acc[ct] = __builtin_amdgcn_mfma_f32_16x16x32_bf16(aHi0, Blo[ct][0], acc[ct], 0, 0, 0);
            acc[ct] = __builtin_amdgcn_mfma_f32_16x16x32_bf16(aLo0, Bhi[ct][0], acc[ct], 0, 0, 0);
            acc[ct] = __builtin_amdgcn_mfma_f32_16x16x32_bf16(aHi1, Bhi[ct][1], acc[ct], 0, 0, 0);
            acc[ct] = __builtin_amdgcn_mfma_f32_16x16x32_bf16(aHi1, Blo[ct][1], acc[ct], 0, 0, 0);
            acc[ct] = __builtin_amdgcn_mfma_f32_16x16x32_bf16(aLo1, Bhi[ct][1], acc[ct], 0, 0, 0);
        }
        // epilogue: D lane -> col (ct*16+r16), row kg*4+reg; f32 dword stores (proven fast)
        float* tb = zbuf + (size_t)tile * 1024;
#pragma unroll
        for (int ct = 0; ct < 4; ++ct) {
#pragma unroll
            for (int reg = 0; reg < 4; ++reg) {
                float z = acc[ct][reg] + biasv[ct];
                tb[(kg * 4 + reg) * 64 + ct * 16 + r16] = z;
                sum[ct] += z;
                ssum[ct] = fmaf(z, z, ssum[ct]);
            }
        }
    }
#pragma unroll
    for (int ct = 0; ct < 4; ++ct) {
        float s = sum[ct];
        s += __shfl_xor(s, 16);
        s += __shfl_xor(s, 32);
        float q = ssum[ct];
        q += __shfl_xor(q, 16);
        q += __shfl_xor(q, 32);
        if (kg == 0) {
            atomicAdd(&stats[128 + ct * 16 + r16], s);
            atomicAdd(&stats[192 + ct * 16 + r16], q);
        }
    }
}

// ---------------- final: out = relu(BN1(z1)) . L2w + L2b ----------------
__global__ void __launch_bounds__(256) k_final(const float* __restrict__ g1, const float* __restrict__ beta1,
                                               const float* __restrict__ L2w, const float* __restrict__ L2b,
                                               const float* __restrict__ zbuf, float* __restrict__ out,
                                               const float* __restrict__ stats) {
    int lane = threadIdx.x & 63;
    int wid = threadIdx.x >> 6;
    int q = lane & 15;     // quad within row
    int rl = lane >> 4;    // row within group of 4
    const float invP = 1.f / (float)PT;
    float s1[4], t1[4], wv[4];
#pragma unroll
    for (int c = 0; c < 4; ++c) {
        int col = q * 4 + c;
        float mu = stats[128 + col] * invP;
        float var = stats[192 + col] * invP - mu * mu;
        float inv = rsqrtf(var + EPSB);
        s1[c] = g1[col] * inv;
        t1[c] = fmaf(-mu, s1[c], beta1[col]);
        wv[c] = L2w[col];
    }
    float bias = L2b[0];
    int waveId = blockIdx.x * 4 + wid;
    int stride = gridDim.x * 16;
    for (int base = waveId * 4; base < PT; base += stride) {
        const float4 zv = *reinterpret_cast<const float4*>(zbuf + (size_t)base * 64 + lane * 4);
        float p;
        p  = fmaxf(fmaf(zv.x, s1[0], t1[0]), 0.f) * wv[0];
        p  = fmaf(fmaxf(fmaf(zv.y, s1[1], t1[1]), 0.f), wv[1], p);
        p  = fmaf(fmaxf(fmaf(zv.z, s1[2], t1[2]), 0.f), wv[2], p);
        p  = fmaf(fmaxf(fmaf(zv.w, s1[3], t1[3]), 0.f), wv[3], p);
        p += __shfl_xor(p, 1);
        p += __shfl_xor(p, 2);
        p += __shfl_xor(p, 4);
        p += __shfl_xor(p, 8);
        if (q == 0) out[base + rl] = p + bias;
    }
}

extern "C" void kernel_launch(void* const* d_in, const int* in_sizes, int n_in,
                              void* d_out, int out_size, void* d_ws, size_t ws_size,
                              hipStream_t stream) {
    const float* atab  = (const float*)d_in[0];
    const float* btab  = (const float*)d_in[1];
    const float* W1    = (const float*)d_in[2];
    const float* b1    = (const float*)d_in[3];
    const float* W2    = (const float*)d_in[4];
    const float* b2    = (const float*)d_in[5];
    const float* We    = (const float*)d_in[6];
    const float* be    = (const float*)d_in[7];
    const float* L0w   = (const float*)d_in[8];
    const float* L0b   = (const float*)d_in[9];
    const float* L1w   = (const float*)d_in[10];
    const float* L1b   = (const float*)d_in[11];
    const float* L2w   = (const float*)d_in[12];
    const float* L2b   = (const float*)d_in[13];
    const float* g0    = (const float*)d_in[14];
    const float* beta0 = (const float*)d_in[15];
    const float* g1    = (const float*)d_in[16];
    const float* beta1 = (const float*)d_in[17];
    const int*   x     = (const int*)d_in[18];
    const int*   eattr = (const int*)d_in[19];
    // d_in[20], d_in[21] = idx0, idx1 (structured; computed arithmetically)
    const int*   epos  = (const int*)d_in[22];
    float* out = (float*)d_out;

    // workspace layout (floats)
    float* ws = (float*)d_ws;
    float* zbuf = ws;                        // PT*64 = 26,214,400 (z1, f32)
    float* A    = zbuf + (size_t)PT * 64;    // 163,840
    float* Bm   = A + (size_t)NN * 64;       // 163,840
    float* ewf  = Bm + (size_t)NN * 64;      // 2,621,440
    float* W1c  = ewf + (size_t)EE * 64;     // 4096
    float* W2c  = W1c + 4096;
    float* Wec  = W2c + 4096;
    float* b1c  = Wec + 4096;                // 64
    float* b2c  = b1c + 64;
    float* bec  = b2c + 64;
    float* stats = bec + 64;                 // 256: sum0,ss0,sum1,ss1
    unsigned short* WBhi = (unsigned short*)(stats + 256);  // 4096 ushort
    unsigned short* WBlo = WBhi + 4096;                     // 4096 ushort
    int* bcount  = (int*)(WBlo + 4096);      // TT
    int* boffs   = bcount + TT;              // TT+1
    int* bcursor = boffs + TT + 1;           // TT
    int* elist   = bcursor + TT;             // EE

    hipMemsetAsync(bcount, 0, TT * sizeof(int), stream);

    k_prep<<<4, 256, 0, stream>>>(W1, b1, W2, b2, We, be, L0w, L0b, L1w,
                                  W1c, W2c, Wec, b1c, b2c, bec, stats, WBhi, WBlo);
    k_nodes<<<NN, 64, 0, stream>>>(atab, x, W1c, W2c, b1c, b2c, A, Bm);
    k_gstats<<<NGr, 256, 0, stream>>>(A, Bm, stats);
    k_edges<<<512, 256, 0, stream>>>(btab, eattr, epos, Wec, bec, ewf, stats, bcount);
    k_scan<<<1, 256, 0, stream>>>(bcount, boffs, bcursor);
    k_fill<<<EE / 256, 256, 0, stream>>>(epos, bcursor, elist);
    k_scorr<<<256, 256, 0, stream>>>(A, Bm, ewf, boffs, elist, stats);
    k_main<<<512, 256, 0, stream>>>(WBhi, WBlo, L1b, g0, beta0, A, Bm, ewf, boffs, elist,
                                    zbuf, stats);
    k_final<<<1024, 256, 0, stream>>>(g1, beta1, L2w, L2b, zbuf, out, stats);
}

// Round 8
// 283.577 us; speedup vs baseline: 2.2199x; 1.0447x over previous
//
#include <hip/hip_runtime.h>
#include <hip/hip_bf16.h>

#define HID 64
#define NGr 16
#define NPG 160
#define NN  2560            // NGr*NPG
#define EE  40960
#define PPG 25600           // NPG*NPG
#define PT  409600          // NGr*PPG
#define TT  25600           // PT/16 tiles (16 pairs each)
#define TPG 1600            // tiles per graph
#define AV  64
#define BV  8
#define EPSB 1e-5f

typedef __attribute__((ext_vector_type(8))) short short8v;   // 8 bf16 (4 VGPRs)
typedef __attribute__((ext_vector_type(4))) float f32x4;

static __device__ __forceinline__ unsigned short bf16_hi(float v) {   // truncate
    return (unsigned short)(__float_as_uint(v) >> 16);
}
static __device__ __forceinline__ unsigned short bf16_rn(float v) {   // round-nearest-even
    unsigned int u = __float_as_uint(v);
    u += 0x7FFFu + ((u >> 16) & 1u);
    return (unsigned short)(u >> 16);
}
static __device__ __forceinline__ float bf16_val(unsigned short h) {
    return __uint_as_float(((unsigned int)h) << 16);
}

// ---------------- prep: combined weights + zero stats + bf16-split L1w ----------------
__global__ void k_prep(const float* __restrict__ W1, const float* __restrict__ b1,
                       const float* __restrict__ W2, const float* __restrict__ b2,
                       const float* __restrict__ We, const float* __restrict__ be,
                       const float* __restrict__ L0w, const float* __restrict__ L0b,
                       const float* __restrict__ L1w,
                       float* __restrict__ W1c, float* __restrict__ W2c, float* __restrict__ Wec,
                       float* __restrict__ b1c, float* __restrict__ b2c, float* __restrict__ bec,
                       float* __restrict__ stats,
                       unsigned short* __restrict__ WBhi, unsigned short* __restrict__ WBlo) {
    int blk = blockIdx.x, tid = threadIdx.x;
    if (blk == 3) {
        stats[tid] = 0.f;                 // 256 threads zero 256 stat floats
        for (int idx = tid; idx < 4096; idx += 256) {
            float w = L1w[idx];
            unsigned short hi = bf16_hi(w);
            float rem = w - bf16_val(hi);
            WBhi[idx] = hi;
            WBlo[idx] = bf16_hi(rem);
        }
        return;
    }
    const float* Wsrc = (blk == 0) ? W1 : (blk == 1) ? W2 : We;
    const float* bsrc = (blk == 0) ? b1 : (blk == 1) ? b2 : be;
    const float* L    = L0w + blk * 64 * 64;
    float* Wdst = (blk == 0) ? W1c : (blk == 1) ? W2c : Wec;
    float* bdst = (blk == 0) ? b1c : (blk == 1) ? b2c : bec;
    for (int idx = tid; idx < 4096; idx += 256) {
        int k = idx >> 6, h = idx & 63;
        float acc = 0.f;
        for (int m = 0; m < 64; ++m) acc = fmaf(Wsrc[k * 64 + m], L[m * 64 + h], acc);
        Wdst[idx] = acc;
    }
    if (tid < 64) {
        int h = tid;
        float acc = (blk == 0) ? L0b[h] : 0.f;
        for (int m = 0; m < 64; ++m) acc = fmaf(bsrc[m], L[m * 64 + h], acc);
        bdst[h] = acc;
    }
}

// ---------------- nodes: x_emb -> A, B (2560 x 64 each); 4 waves/block, one node/wave --------
__global__ void __launch_bounds__(256) k_nodes(const float* __restrict__ atab, const int* __restrict__ x,
                        const float* __restrict__ W1c, const float* __restrict__ W2c,
                        const float* __restrict__ b1c, const float* __restrict__ b2c,
                        float* __restrict__ A, float* __restrict__ Bm) {
    int w = threadIdx.x >> 6, h = threadIdx.x & 63;
    int n = blockIdx.x * 4 + w;
    __shared__ float xe[4][64];
    float v = 0.f;
#pragma unroll
    for (int c = 0; c < 9; ++c) v += atab[c * AV * HID + x[n * 9 + c] * HID + h];
    xe[w][h] = v;                         // wave-private region, wave-synchronous
    float a = b1c[h], b = b2c[h];
#pragma unroll
    for (int k = 0; k < 64; ++k) {
        float xk = xe[w][k];
        a = fmaf(xk, W1c[k * 64 + h], a);
        b = fmaf(xk, W2c[k * 64 + h], b);
    }
    A[n * 64 + h] = a;
    Bm[n * 64 + h] = b;
}

// ---------------- gstats: analytic BN0 stats from A,B (dense part) ----------------
__global__ void k_gstats(const float* __restrict__ A, const float* __restrict__ Bm,
                         float* __restrict__ stats) {
    int g = blockIdx.x;
    int h = threadIdx.x & 63, w = threadIdx.x >> 6;
    float sA = 0.f, sA2 = 0.f, sB = 0.f, sB2 = 0.f;
    for (int n = w; n < NPG; n += 4) {
        float a = A[(size_t)(g * NPG + n) * 64 + h];
        float b = Bm[(size_t)(g * NPG + n) * 64 + h];
        sA += a; sA2 = fmaf(a, a, sA2);
        sB += b; sB2 = fmaf(b, b, sB2);
    }
    __shared__ float ls[4][4][64];
    ls[w][0][h] = sA; ls[w][1][h] = sA2; ls[w][2][h] = sB; ls[w][3][h] = sB2;
    __syncthreads();
    if (w == 0) {
        sA  = ls[0][0][h] + ls[1][0][h] + ls[2][0][h] + ls[3][0][h];
        sA2 = ls[0][1][h] + ls[1][1][h] + ls[2][1][h] + ls[3][1][h];
        sB  = ls[0][2][h] + ls[1][2][h] + ls[2][2][h] + ls[3][2][h];
        sB2 = ls[0][3][h] + ls[1][3][h] + ls[2][3][h] + ls[3][3][h];
        atomicAdd(&stats[h], 160.f * (sA + sB));
        atomicAdd(&stats[64 + h], 160.f * (sA2 + sB2) + 2.f * sA * sB);
    }
}

// ---------------- edges: ew = bond_emb @ Wec + bec -> ewf; sum0 += ew; bucket counts ----------------
__global__ void __launch_bounds__(256) k_edges(const float* __restrict__ btab, const int* __restrict__ eattr,
                                               const int* __restrict__ epos,
                                               const float* __restrict__ Wec, const float* __restrict__ bec,
                                               float* __restrict__ ewf, float* __restrict__ stats,
                                               int* __restrict__ bcount) {
    int h = threadIdx.x & 63;
    int el = threadIdx.x >> 6;
    __shared__ float ea[4][64];
    float ssum = 0.f;
    for (int base = blockIdx.x * 4; base < EE; base += gridDim.x * 4) {
        int e = base + el;
        float v = 0.f;
#pragma unroll
        for (int c = 0; c < 3; ++c) v += btab[c * BV * HID + eattr[e * 3 + c] * HID + h];
        ea[el][h] = v;                   // wave-local, wave-synchronous
        float ew = bec[h];
#pragma unroll
        for (int k = 0; k < 64; ++k) ew = fmaf(ea[el][k], Wec[k * 64 + h], ew);
        ewf[(size_t)e * 64 + h] = ew;
        ssum += ew;
        if (h == 0) atomicAdd(&bcount[epos[e] >> 4], 1);
    }
    atomicAdd(&stats[h], ssum);
}

// ---------------- scan: exclusive prefix of bcount[TT] -> boffs, bcursor (1024 threads) --------
__global__ void k_scan(const int* __restrict__ bcount, int* __restrict__ boffs,
                       int* __restrict__ bcursor) {
    __shared__ int part[1024];
    int tid = threadIdx.x;
    int base = tid * (TT / 1024);
    int s = 0;
    for (int q = 0; q < TT / 1024; ++q) s += bcount[base + q];
    part[tid] = s;
    __syncthreads();
    for (int d = 1; d < 1024; d <<= 1) {
        int v = (tid >= d) ? part[tid - d] : 0;
        __syncthreads();
        part[tid] += v;
        __syncthreads();
    }
    int run = part[tid] - s;   // exclusive prefix
    for (int q = 0; q < TT / 1024; ++q) {
        int c = bcount[base + q];
        boffs[base + q] = run;
        bcursor[base + q] = run;
        run += c;
    }
    if (tid == 1023) boffs[TT] = run;
}

// ---------------- fill: elist[slot] = (e<<4) | jslot ----------------
__global__ void k_fill(const int* __restrict__ epos, int* __restrict__ bcursor,
                       int* __restrict__ elist) {
    int e = blockIdx.x * 256 + threadIdx.x;
    if (e >= EE) return;
    int p = epos[e];
    int t = p >> 4, jj = p & 15;
    int slot = atomicAdd(&bcursor[t], 1);
    elist[slot] = (e << 4) | jj;
}

// ---------------- scorr: sparse ss0 correction ----------------
__global__ void __launch_bounds__(256) k_scorr(const float* __restrict__ A, const float* __restrict__ Bm,
                                               const float* __restrict__ ewf,
                                               const int* __restrict__ boffs, const int* __restrict__ elist,
                                               float* __restrict__ stats) {
    __shared__ float run[4][16][64];
    int h = threadIdx.x & 63, w = threadIdx.x >> 6;
#pragma unroll
    for (int jj = 0; jj < 16; ++jj) run[w][jj][h] = 0.f;
    float ssacc = 0.f;
    int wave = blockIdx.x * 4 + w;
    int nw = gridDim.x * 4;
    for (int t = wave; t < TT; t += nw) {
        int be = boffs[t], en = boffs[t + 1];
        if (be == en) continue;
        int g = t / TPG;
        int rem = t - g * TPG;
        int i = rem / 10;
        int j0 = (rem - i * 10) << 4;
        float a = A[(size_t)(g * NPG + i) * 64 + h];
        for (int q = be; q < en; ++q) {
            int pk = elist[q];
            int e = pk >> 4, jj = pk & 15;
            float ew = ewf[(size_t)e * 64 + h];
            float base = a + Bm[(size_t)(g * NPG + j0 + jj) * 64 + h];
            float r = run[w][jj][h];
            ssacc += 2.f * (base + r) * ew + ew * ew;
            run[w][jj][h] = r + ew;
        }
        for (int q = be; q < en; ++q) run[w][elist[q] & 15][h] = 0.f;
    }
    atomicAdd(&stats[64 + h], ssacc);
}

// ---------------- main (fused dense+edges+mid): z0 in regs -> BN0 -> relu -> MFMA -> z1 bf16-packed ----
// Grid MUST stay small (512): prologue-amortization-bound; 1600+ blocks measured 2x slower (R6).
// Packed store: uint2 per lane per ct -> 512B contiguous per wave-store (dwordx2, coalesced).
__global__ void __launch_bounds__(256) k_main(const unsigned short* __restrict__ WBhi,
                                              const unsigned short* __restrict__ WBlo,
                                              const float* __restrict__ L1b,
                                              const float* __restrict__ g0, const float* __restrict__ beta0,
                                              const float* __restrict__ A, const float* __restrict__ Bm,
                                              const float* __restrict__ ewf,
                                              const int* __restrict__ boffs, const int* __restrict__ elist,
                                              uint2* __restrict__ zpk, float* __restrict__ stats) {
    int lane = threadIdx.x & 63;
    int wid  = blockIdx.x * 4 + (threadIdx.x >> 6);
    int nWaves = gridDim.x * 4;
    int r16 = lane & 15;
    int kg  = lane >> 4;

    const float invP = 1.f / (float)PT;
    float s0a[8], t0a[8], s0b[8], t0b[8];
#pragma unroll
    for (int j = 0; j < 8; ++j) {
        int k = kg * 8 + j;
        float mu = stats[k] * invP;
        float var = stats[64 + k] * invP - mu * mu;
        float inv = rsqrtf(var + EPSB);
        s0a[j] = g0[k] * inv;
        t0a[j] = fmaf(-mu, s0a[j], beta0[k]);
        int k2 = k + 32;
        float mu2 = stats[k2] * invP;
        float var2 = stats[64 + k2] * invP - mu2 * mu2;
        float inv2 = rsqrtf(var2 + EPSB);
        s0b[j] = g0[k2] * inv2;
        t0b[j] = fmaf(-mu2, s0b[j], beta0[k2]);
    }
    short8v Bhi[4][2], Blo[4][2];
#pragma unroll
    for (int ct = 0; ct < 4; ++ct)
#pragma unroll
        for (int ks = 0; ks < 2; ++ks)
#pragma unroll
            for (int j = 0; j < 8; ++j) {
                int k = ks * 32 + kg * 8 + j;
                int idx = k * 64 + ct * 16 + r16;
                Bhi[ct][ks][j] = (short)WBhi[idx];
                Blo[ct][ks][j] = (short)WBlo[idx];
            }
    float biasv[4];
#pragma unroll
    for (int ct = 0; ct < 4; ++ct) biasv[ct] = L1b[ct * 16 + r16];

    float sum[4] = {0.f, 0.f, 0.f, 0.f}, ssum[4] = {0.f, 0.f, 0.f, 0.f};

    for (int tile = wid; tile < TT; tile += nWaves) {
        int g = tile / TPG;
        int rem = tile - g * TPG;
        int i = rem / 10;
        int j0 = (rem - i * 10) << 4;
        const float* Ar = A + (size_t)(g * NPG + i) * 64;
        const float* Br = Bm + (size_t)(g * NPG + j0 + r16) * 64;
        float4 a0 = *reinterpret_cast<const float4*>(Ar + kg * 8);
        float4 a1 = *reinterpret_cast<const float4*>(Ar + kg * 8 + 4);
        float4 a2 = *reinterpret_cast<const float4*>(Ar + 32 + kg * 8);
        float4 a3 = *reinterpret_cast<const float4*>(Ar + 32 + kg * 8 + 4);
        float4 b0 = *reinterpret_cast<const float4*>(Br + kg * 8);
        float4 b1 = *reinterpret_cast<const float4*>(Br + kg * 8 + 4);
        float4 b2 = *reinterpret_cast<const float4*>(Br + 32 + kg * 8);
        float4 b3 = *reinterpret_cast<const float4*>(Br + 32 + kg * 8 + 4);
        float ha[8] = {a0.x + b0.x, a0.y + b0.y, a0.z + b0.z, a0.w + b0.w,
                       a1.x + b1.x, a1.y + b1.y, a1.z + b1.z, a1.w + b1.w};
        float hb[8] = {a2.x + b2.x, a2.y + b2.y, a2.z + b2.z, a2.w + b2.w,
                       a3.x + b3.x, a3.y + b3.y, a3.z + b3.z, a3.w + b3.w};
        int be = boffs[tile], en = boffs[tile + 1];
        for (int q = be; q < en; ++q) {
            int pk = elist[q];
            if (r16 == (pk & 15)) {
                const float* er = ewf + (size_t)(pk >> 4) * 64;
                float4 e0 = *reinterpret_cast<const float4*>(er + kg * 8);
                float4 e1 = *reinterpret_cast<const float4*>(er + kg * 8 + 4);
                float4 e2 = *reinterpret_cast<const float4*>(er + 32 + kg * 8);
                float4 e3 = *reinterpret_cast<const float4*>(er + 32 + kg * 8 + 4);
                ha[0] += e0.x; ha[1] += e0.y; ha[2] += e0.z; ha[3] += e0.w;
                ha[4] += e1.x; ha[5] += e1.y; ha[6] += e1.z; ha[7] += e1.w;
                hb[0] += e2.x; hb[1] += e2.y; hb[2] += e2.z; hb[3] += e2.w;
                hb[4] += e3.x; hb[5] += e3.y; hb[6] += e3.z; hb[7] += e3.w;
            }
        }
        short8v aHi0, aLo0, aHi1, aLo1;
#pragma unroll
        for (int j = 0; j < 8; ++j) {
            float hv = fmaxf(fmaf(ha[j], s0a[j], t0a[j]), 0.f);
            unsigned short hi = bf16_hi(hv);
            float remv = hv - bf16_val(hi);
            aHi0[j] = (short)hi;
            aLo0[j] = (short)bf16_hi(remv);
            float hv2 = fmaxf(fmaf(hb[j], s0b[j], t0b[j]), 0.f);
            unsigned short hi2 = bf16_hi(hv2);
            float rem2 = hv2 - bf16_val(hi2);
            aHi1[j] = (short)hi2;
            aLo1[j] = (short)bf16_hi(rem2);
        }
        f32x4 acc[4];
#pragma unroll
        for (int ct = 0; ct < 4; ++ct) acc[ct] = (f32x4){0.f, 0.f, 0.f, 0.f};
#pragma unroll
        for (int ct = 0; ct < 4; ++ct) {
            acc[ct] = __builtin_amdgcn_mfma_f32_16x16x32_bf16(aHi0, Bhi[ct][0], acc[ct], 0, 0, 0);
            acc[ct] = __builtin_amdgcn_mfma_f32_16x16x32_bf16(aHi0, Blo[ct][0], acc[ct], 0, 0, 0);
            acc[ct] = __builtin_amdgcn_mfma_f32_16x16x32_bf16(aLo0, Bhi[ct][0], acc[ct], 0, 0, 0);
            acc[ct] = __builtin_amdgcn_mfma_f32_16x16x32_bf16(aHi1, Bhi[ct][1], acc[ct], 0, 0, 0);
            acc[ct] = __builtin_amdgcn_mfma_f32_16x16x32_bf16(aHi1, Blo[ct][1], acc[ct], 0, 0, 0);
            acc[ct] = __builtin_amdgcn_mfma_f32_16x16x32_bf16(aLo1, Bhi[ct][1], acc[ct], 0, 0, 0);
        }
        // epilogue: pack rows (4kg..4kg+3, col ct*16+r16) into uint2; coalesced dwordx2 store
        uint2* tz = zpk + (size_t)tile * 256 + lane;
#pragma unroll
        for (int ct = 0; ct < 4; ++ct) {
            float z0 = acc[ct][0] + biasv[ct];
            float z1 = acc[ct][1] + biasv[ct];
            float z2 = acc[ct][2] + biasv[ct];
            float z3 = acc[ct][3] + biasv[ct];
            unsigned short u0 = bf16_rn(z0), u1 = bf16_rn(z1), u2 = bf16_rn(z2), u3 = bf16_rn(z3);
            float r0 = bf16_val(u0), r1 = bf16_val(u1), r2 = bf16_val(u2), r3 = bf16_val(u3);
            sum[ct] += (r0 + r1) + (r2 + r3);
            ssum[ct] += fmaf(r0, r0, fmaf(r1, r1, fmaf(r2, r2, r3 * r3)));
            uint2 pk;
            pk.x = (unsigned)u0 | ((unsigned)u1 << 16);
            pk.y = (unsigned)u2 | ((unsigned)u3 << 16);
            tz[ct * 64] = pk;
        }
    }
#pragma unroll
    for (int ct = 0; ct < 4; ++ct) {
        float s = sum[ct];
        s += __shfl_xor(s, 16);
        s += __shfl_xor(s, 32);
        float q = ssum[ct];
        q += __shfl_xor(q, 16);
        q += __shfl_xor(q, 32);
        if (kg == 0) {
            atomicAdd(&stats[128 + ct * 16 + r16], s);
            atomicAdd(&stats[192 + ct * 16 + r16], q);
        }
    }
}

// ---------------- final: out = relu(BN1(z1)) . L2w + L2b  (packed bf16 tile layout) ----------------
__global__ void __launch_bounds__(256) k_final(const float* __restrict__ g1, const float* __restrict__ beta1,
                                               const float* __restrict__ L2w, const float* __restrict__ L2b,
                                               const uint2* __restrict__ zpk, float* __restrict__ out,
                                               const float* __restrict__ stats) {
    int lane = threadIdx.x & 63;
    int wid = blockIdx.x * 4 + (threadIdx.x >> 6);
    int nW = gridDim.x * 4;
    int r16 = lane & 15, kg = lane >> 4;
    const float invP = 1.f / (float)PT;
    float s1c[4], t1c[4], wv[4];
#pragma unroll
    for (int ct = 0; ct < 4; ++ct) {
        int col = ct * 16 + r16;
        float mu = stats[128 + col] * invP;
        float var = stats[192 + col] * invP - mu * mu;
        float inv = rsqrtf(var + EPSB);
        s1c[ct] = g1[col] * inv;
        t1c[ct] = fmaf(-mu, s1c[ct], beta1[col]);
        wv[ct] = L2w[col];
    }
    float obias = L2b[0];
    for (int tile = wid; tile < TT; tile += nW) {
        const uint2* tz = zpk + (size_t)tile * 256 + lane;
        uint2 cc[4] = {tz[0], tz[64], tz[128], tz[192]};
        float p0 = 0.f, p1 = 0.f, p2 = 0.f, p3 = 0.f;
#pragma unroll
        for (int ct = 0; ct < 4; ++ct) {
            float z0 = bf16_val((unsigned short)(cc[ct].x & 0xffffu));
            float z1 = bf16_val((unsigned short)(cc[ct].x >> 16));
            float z2 = bf16_val((unsigned short)(cc[ct].y & 0xffffu));
            float z3 = bf16_val((unsigned short)(cc[ct].y >> 16));
            p0 = fmaf(fmaxf(fmaf(z0, s1c[ct], t1c[ct]), 0.f), wv[ct], p0);
            p1 = fmaf(fmaxf(fmaf(z1, s1c[ct], t1c[ct]), 0.f), wv[ct], p1);
            p2 = fmaf(fmaxf(fmaf(z2, s1c[ct], t1c[ct]), 0.f), wv[ct], p2);
            p3 = fmaf(fmaxf(fmaf(z3, s1c[ct], t1c[ct]), 0.f), wv[ct], p3);
        }
#pragma unroll
        for (int d = 1; d < 16; d <<= 1) {
            p0 += __shfl_xor(p0, d);
            p1 += __shfl_xor(p1, d);
            p2 += __shfl_xor(p2, d);
            p3 += __shfl_xor(p3, d);
        }
        if (r16 == 0) {
            float4 o = {p0 + obias, p1 + obias, p2 + obias, p3 + obias};
            *reinterpret_cast<float4*>(out + tile * 16 + kg * 4) = o;
        }
    }
}

extern "C" void kernel_launch(void* const* d_in, const int* in_sizes, int n_in,
                              void* d_out, int out_size, void* d_ws, size_t ws_size,
                              hipStream_t stream) {
    const float* atab  = (const float*)d_in[0];
    const float* btab  = (const float*)d_in[1];
    const float* W1    = (const float*)d_in[2];
    const float* b1    = (const float*)d_in[3];
    const float* W2    = (const float*)d_in[4];
    const float* b2    = (const float*)d_in[5];
    const float* We    = (const float*)d_in[6];
    const float* be    = (const float*)d_in[7];
    const float* L0w   = (const float*)d_in[8];
    const float* L0b   = (const float*)d_in[9];
    const float* L1w   = (const float*)d_in[10];
    const float* L1b   = (const float*)d_in[11];
    const float* L2w   = (const float*)d_in[12];
    const float* L2b   = (const float*)d_in[13];
    const float* g0    = (const float*)d_in[14];
    const float* beta0 = (const float*)d_in[15];
    const float* g1    = (const float*)d_in[16];
    const float* beta1 = (const float*)d_in[17];
    const int*   x     = (const int*)d_in[18];
    const int*   eattr = (const int*)d_in[19];
    // d_in[20], d_in[21] = idx0, idx1 (structured; computed arithmetically)
    const int*   epos  = (const int*)d_in[22];
    float* out = (float*)d_out;

    // workspace layout (floats)
    float* ws = (float*)d_ws;
    float* zpk_f = ws;                       // PT*64 bf16 = 13,107,200 floats (52.4 MB)
    float* A    = zpk_f + 13107200;          // 163,840
    float* Bm   = A + (size_t)NN * 64;       // 163,840
    float* ewf  = Bm + (size_t)NN * 64;      // 2,621,440
    float* W1c  = ewf + (size_t)EE * 64;     // 4096
    float* W2c  = W1c + 4096;
    float* Wec  = W2c + 4096;
    float* b1c  = Wec + 4096;                // 64
    float* b2c  = b1c + 64;
    float* bec  = b2c + 64;
    float* stats = bec + 64;                 // 256: sum0,ss0,sum1,ss1
    unsigned short* WBhi = (unsigned short*)(stats + 256);  // 4096 ushort
    unsigned short* WBlo = WBhi + 4096;                     // 4096 ushort
    int* bcount  = (int*)(WBlo + 4096);      // TT
    int* boffs   = bcount + TT;              // TT+1
    int* bcursor = boffs + TT + 1;           // TT
    int* elist   = bcursor + TT;             // EE

    uint2* zpk = (uint2*)zpk_f;

    hipMemsetAsync(bcount, 0, TT * sizeof(int), stream);

    k_prep<<<4, 256, 0, stream>>>(W1, b1, W2, b2, We, be, L0w, L0b, L1w,
                                  W1c, W2c, Wec, b1c, b2c, bec, stats, WBhi, WBlo);
    k_nodes<<<NN / 4, 256, 0, stream>>>(atab, x, W1c, W2c, b1c, b2c, A, Bm);
    k_gstats<<<NGr, 256, 0, stream>>>(A, Bm, stats);
    k_edges<<<512, 256, 0, stream>>>(btab, eattr, epos, Wec, bec, ewf, stats, bcount);
    k_scan<<<1, 1024, 0, stream>>>(bcount, boffs, bcursor);
    k_fill<<<EE / 256, 256, 0, stream>>>(epos, bcursor, elist);
    k_scorr<<<256, 256, 0, stream>>>(A, Bm, ewf, boffs, elist, stats);
    k_main<<<512, 256, 0, stream>>>(WBhi, WBlo, L1b, g0, beta0, A, Bm, ewf, boffs, elist,
                                    zpk, stats);
    k_final<<<1024, 256, 0, stream>>>(g1, beta1, L2w, L2b, zpk, out, stats);
}